// Round 2
// 1462.419 us; speedup vs baseline: 1.1396x; 1.1396x over previous
//
#include <hip/hip_runtime.h>
#include <hip/hip_bf16.h>
#include <stdint.h>

typedef __hip_bfloat16 bf16;
typedef __attribute__((ext_vector_type(8))) short short8;
typedef __attribute__((ext_vector_type(4))) float f32x4;

#define NE 8
#define NH 12
#define HDIM 64
#define WINSZ 128
#define NB 2
#define SEQ 1024
#define DIM 768
#define FFN 3072
#define NTOK 2048   // NB*SEQ
#define SCP (WINSZ + 4)   // padded score stride: breaks per-head same-bank aliasing

__device__ __forceinline__ float bf2f(unsigned int u) {
  union { unsigned int i; float f; } v; v.i = u << 16; return v.f;
}

// ---------------- transpose + cast: in f32 (z, K, N) -> out bf16 (z, N, K) ----
__global__ void transpose_k(const float* __restrict__ in, bf16* __restrict__ out,
                            int K, int N) {
  __shared__ float s[32][33];
  const size_t zoff = (size_t)blockIdx.z * K * N;
  int n = blockIdx.x * 32 + threadIdx.x;
  int k = blockIdx.y * 32 + threadIdx.y;
  s[threadIdx.y][threadIdx.x] = in[zoff + (size_t)k * N + n];
  __syncthreads();
  int n2 = blockIdx.x * 32 + threadIdx.y;
  int k2 = blockIdx.y * 32 + threadIdx.x;
  out[zoff + (size_t)n2 * K + k2] = __float2bfloat16(s[threadIdx.x][threadIdx.y]);
}

// ---------------- cast f32 -> bf16, 8 elems/thread ----------------
__global__ void cast_k(const float* __restrict__ in, bf16* __restrict__ out) {
  size_t i = ((size_t)blockIdx.x * 256 + threadIdx.x) * 8;
  float4 a = *(const float4*)(in + i);
  float4 b = *(const float4*)(in + i + 4);
  unsigned short r[8];
  float v[8] = {a.x, a.y, a.z, a.w, b.x, b.y, b.z, b.w};
  #pragma unroll
  for (int c = 0; c < 8; c++) {
    bf16 t = __float2bfloat16(v[c]);
    r[c] = *(unsigned short*)&t;
  }
  uint4 o;
  o.x = r[0] | ((unsigned)r[1] << 16); o.y = r[2] | ((unsigned)r[3] << 16);
  o.z = r[4] | ((unsigned)r[5] << 16); o.w = r[6] | ((unsigned)r[7] << 16);
  *(uint4*)((unsigned short*)out + i) = o;
}

// ---------------- router (fp32 in): logits, softmax, argmax, stats ----------
__global__ void router_k(const float* __restrict__ x, const float* __restrict__ gw,
                         int* __restrict__ idx, int* __restrict__ cnt,
                         float* __restrict__ psum) {
  const int t = blockIdx.x;
  const int lane = threadIdx.x; // 64 threads
  const float* xr = x + (size_t)t * DIM;
  float acc[NE];
  #pragma unroll
  for (int e = 0; e < NE; e++) acc[e] = 0.f;
  for (int d = lane; d < DIM; d += 64) {
    float xv = xr[d];
    float4 g0 = *(const float4*)(gw + (size_t)d * NE);
    float4 g1 = *(const float4*)(gw + (size_t)d * NE + 4);
    acc[0] += xv * g0.x; acc[1] += xv * g0.y;
    acc[2] += xv * g0.z; acc[3] += xv * g0.w;
    acc[4] += xv * g1.x; acc[5] += xv * g1.y;
    acc[6] += xv * g1.z; acc[7] += xv * g1.w;
  }
  #pragma unroll
  for (int o = 32; o > 0; o >>= 1) {
    #pragma unroll
    for (int e = 0; e < NE; e++) acc[e] += __shfl_xor(acc[e], o, 64);
  }
  if (lane == 0) {
    float lg[NE];
    #pragma unroll
    for (int e = 0; e < NE; e++) lg[e] = acc[e] * 0.5f;  // TEMP=2.0
    float mx = lg[0]; int am = 0;
    #pragma unroll
    for (int e = 1; e < NE; e++) if (lg[e] > mx) { mx = lg[e]; am = e; }
    float s = 0.f, p[NE];
    #pragma unroll
    for (int e = 0; e < NE; e++) { p[e] = __expf(lg[e] - mx); s += p[e]; }
    float inv = 1.f / s;
    #pragma unroll
    for (int e = 0; e < NE; e++) atomicAdd(&psum[e], p[e] * inv);
    atomicAdd(&cnt[am], 1);
    idx[t] = am;
  }
}

// ---------------- scan offsets + aux loss (fp32 out) ----------------
__global__ void scan_k(const int* __restrict__ cnt, const float* __restrict__ psum,
                       int* __restrict__ offs, float* __restrict__ aux_out) {
  if (threadIdx.x == 0 && blockIdx.x == 0) {
    int o = 0;
    for (int e = 0; e < NE; e++) { offs[e] = o; o += cnt[e]; }
    offs[NE] = o;
    float aux = 0.f;
    for (int e = 0; e < NE; e++)
      aux += ((float)cnt[e] / (float)NTOK) * (psum[e] / (float)NTOK);
    aux_out[0] = aux * (float)NE;
  }
}

// ---------------- scatter tokens into per-expert groups ----------------
__global__ void scatter_k(const int* __restrict__ idx, const int* __restrict__ offs,
                          int* __restrict__ cursor, int* __restrict__ perm) {
  int t = blockIdx.x * 256 + threadIdx.x;
  if (t < NTOK) {
    int e = idx[t];
    int p = atomicAdd(&cursor[e], 1);
    perm[offs[e] + p] = t;
  }
}

// ---------------- K column-means per (expert,batch) ----------------
__global__ void kmean_k(const bf16* __restrict__ Kb, float* __restrict__ km) {
  int d = blockIdx.x * 256 + threadIdx.x;           // 0..767
  int z = blockIdx.y;                               // e*2+b
  int j0 = blockIdx.z * 128;
  const unsigned short* base = (const unsigned short*)Kb + (size_t)z * SEQ * DIM;
  float s = 0.f;
  for (int j = j0; j < j0 + 128; j++) s += bf2f(base[(size_t)j * DIM + d]);
  atomicAdd(&km[z * DIM + d], s * (1.f / (float)SEQ));
}

// ---------------- GEMM: C[M,N] = A[M,K] @ Bt[N,K]^T  (bf16 in, CT out, f32 acc) ----
template <bool GROUPED, bool GATHER, bool SCATTER, typename CT>
__global__ __launch_bounds__(256)
void gemm_bt(const bf16* __restrict__ A, const bf16* __restrict__ Bt, size_t Bstride,
             CT* __restrict__ C, size_t Cstride, int N, int K,
             const int* __restrict__ offs, const int* __restrict__ perm) {
  __shared__ alignas(16) bf16 As[128 * 64];
  __shared__ alignas(16) bf16 Bs[128 * 64];
  const int tid = threadIdx.x;
  const int bz = blockIdx.z;
  int off = 0, cnt = NTOK;
  if constexpr (GROUPED) { off = offs[bz]; cnt = offs[bz + 1] - off; }
  const int m_base = blockIdx.y * 128;
  if (m_base >= cnt) return;
  const int n_base = blockIdx.x * 128;
  const bf16* Be = Bt + (size_t)bz * Bstride;
  CT* Ce = C + (size_t)bz * Cstride;

  const bf16* aptr[4];
  const bf16* bptr[4];
  #pragma unroll
  for (int it = 0; it < 4; ++it) {
    int cid = it * 256 + tid;
    int row = cid >> 3, c8 = cid & 7;
    int r = m_base + row;
    int arow;
    if constexpr (GROUPED) {
      int rr = (r < cnt) ? r : (cnt - 1);
      arow = GATHER ? perm[off + rr] : (off + rr);
    } else {
      arow = r;
    }
    aptr[it] = A + (size_t)arow * K + c8 * 8;
    bptr[it] = Be + (size_t)(n_base + row) * K + c8 * 8;
  }

  f32x4 acc[4][4];
  #pragma unroll
  for (int i = 0; i < 4; i++)
    #pragma unroll
    for (int j = 0; j < 4; j++) acc[i][j] = {0.f, 0.f, 0.f, 0.f};

  const int lane = tid & 63;
  const int w = tid >> 6;
  const int wm = (w & 1) * 64, wn = (w >> 1) * 64;
  const int lrow = lane & 15;
  const int lk = (lane >> 4) * 8;

  for (int k0 = 0; k0 < K; k0 += 64) {
    uint4 av[4], bv[4];
    #pragma unroll
    for (int it = 0; it < 4; ++it) {
      av[it] = *(const uint4*)(aptr[it] + k0);
      bv[it] = *(const uint4*)(bptr[it] + k0);
    }
    __syncthreads();   // previous iteration's LDS reads complete before overwrite
    #pragma unroll
    for (int it = 0; it < 4; ++it) {
      *(uint4*)((char*)As + it * 4096 + tid * 16) = av[it];
      *(uint4*)((char*)Bs + it * 4096 + tid * 16) = bv[it];
    }
    __syncthreads();
    #pragma unroll
    for (int kk = 0; kk < 64; kk += 32) {
      short8 af[4], bfr[4];
      #pragma unroll
      for (int mt = 0; mt < 4; mt++)
        af[mt] = *(const short8*)&As[(wm + mt * 16 + lrow) * 64 + kk + lk];
      #pragma unroll
      for (int nt = 0; nt < 4; nt++)
        bfr[nt] = *(const short8*)&Bs[(wn + nt * 16 + lrow) * 64 + kk + lk];
      #pragma unroll
      for (int mt = 0; mt < 4; mt++)
        #pragma unroll
        for (int nt = 0; nt < 4; nt++)
          acc[mt][nt] = __builtin_amdgcn_mfma_f32_16x16x32_bf16(
              af[mt], bfr[nt], acc[mt][nt], 0, 0, 0);
    }
  }

  #pragma unroll
  for (int mt = 0; mt < 4; mt++) {
    #pragma unroll
    for (int r = 0; r < 4; r++) {
      int row_in = wm + mt * 16 + (lane >> 4) * 4 + r;
      int rr = m_base + row_in;
      if (GROUPED && rr >= cnt) continue;
      int crow;
      if constexpr (GROUPED) crow = SCATTER ? perm[off + rr] : (off + rr);
      else crow = rr;
      size_t base = (size_t)crow * N + n_base + wn + (lane & 15);
      #pragma unroll
      for (int nt = 0; nt < 4; nt++) {
        if constexpr (sizeof(CT) == 2)
          Ce[base + nt * 16] = __float2bfloat16(acc[mt][nt][r]);
        else
          Ce[base + nt * 16] = acc[mt][nt][r];
      }
    }
  }
}

// ---------------- sliding-window attention w/ reynolds modulation ----------------
// v2: wave-parallel softmax (12h x 16 lanes, shfl reduce), vectorized PV
// (uint4 V loads, 8 outputs/thread, shfl pair-combine), padded score stride.
__global__ __launch_bounds__(256)
void attn_k(const bf16* __restrict__ Q, const bf16* __restrict__ Kb,
            const bf16* __restrict__ Vb, const float* __restrict__ km,
            const int* __restrict__ idx, bf16* __restrict__ outp) {
  __shared__ alignas(16) float qf[DIM];
  __shared__ float means[NH];
  __shared__ float sc[NH][SCP];
  const int t = blockIdx.x;
  const int tid = threadIdx.x;
  const int b = t >> 10, i = t & (SEQ - 1);
  const int e = idx[t];
  const int z = e * 2 + b;
  const unsigned short* Kbase = (const unsigned short*)Kb + (size_t)z * SEQ * DIM;
  const unsigned short* Vbase = (const unsigned short*)Vb + (size_t)z * SEQ * DIM;
  const unsigned short* qrow = (const unsigned short*)Q + (size_t)t * DIM;

  for (int d = tid; d < DIM; d += 256) qf[d] = bf2f(qrow[d]);
  __syncthreads();

  // means: 12 heads x 16 lanes, float4 partial dot + shfl-16 reduce
  if (tid < 192) {
    const int h = tid >> 4, l = tid & 15;
    float4 kv = *(const float4*)(km + (size_t)z * DIM + h * HDIM + l * 4);
    float4 qv = *(const float4*)(qf + h * HDIM + l * 4);
    float s = qv.x * kv.x + qv.y * kv.y + qv.z * kv.z + qv.w * kv.w;
    s += __shfl_xor(s, 1); s += __shfl_xor(s, 2);
    s += __shfl_xor(s, 4); s += __shfl_xor(s, 8);
    if (l == 0) means[h] = s * 0.125f;
  }
  __syncthreads();

  // window scores + reynolds (1536 slots / 256 threads = 6 each)
  for (int slot = tid; slot < NH * WINSZ; slot += 256) {
    int h = slot >> 7, jw = slot & (WINSZ - 1);
    int j = i - (WINSZ - 1) + jw;
    float sv = -1e30f;
    if (j >= 0) {
      const uint4* kp = (const uint4*)(Kbase + (size_t)j * DIM + h * HDIM);
      const float* qh = qf + h * HDIM;
      float a = 0.f;
      #pragma unroll
      for (int c = 0; c < 8; c++) {
        uint4 u = kp[c];
        a += qh[c*8+0]*bf2f(u.x & 0xffffu) + qh[c*8+1]*bf2f(u.x >> 16)
           + qh[c*8+2]*bf2f(u.y & 0xffffu) + qh[c*8+3]*bf2f(u.y >> 16)
           + qh[c*8+4]*bf2f(u.z & 0xffffu) + qh[c*8+5]*bf2f(u.z >> 16)
           + qh[c*8+6]*bf2f(u.w & 0xffffu) + qh[c*8+7]*bf2f(u.w >> 16);
      }
      float s = a * 0.125f;
      float sig = 1.f / (1.f + __expf(-s));
      sv = 1.1f * s - 0.1f * sig * sig - 0.1f * fabsf(s - means[h]);
    }
    sc[h][jw] = sv;
  }
  __syncthreads();

  // per-head softmax: head h handled by 16 lanes, 8 slots/lane, shfl-16 reduce
  if (tid < 192) {
    const int h = tid >> 4, l = tid & 15;
    float vloc[8];
    float m = -1e30f;
    #pragma unroll
    for (int k = 0; k < 8; k++) {
      vloc[k] = sc[h][l + 16 * k];
      m = fmaxf(m, vloc[k]);
    }
    m = fmaxf(m, __shfl_xor(m, 1)); m = fmaxf(m, __shfl_xor(m, 2));
    m = fmaxf(m, __shfl_xor(m, 4)); m = fmaxf(m, __shfl_xor(m, 8));
    float ssum = 0.f;
    #pragma unroll
    for (int k = 0; k < 8; k++) {
      float ev = (vloc[k] > -1e29f) ? __expf(vloc[k] - m) : 0.f;
      vloc[k] = ev;
      ssum += ev;
    }
    ssum += __shfl_xor(ssum, 1); ssum += __shfl_xor(ssum, 2);
    ssum += __shfl_xor(ssum, 4); ssum += __shfl_xor(ssum, 8);
    float inv = 1.f / ssum;
    #pragma unroll
    for (int k = 0; k < 8; k++) sc[h][l + 16 * k] = vloc[k] * inv;
  }
  __syncthreads();

  // P@V: 96 (h,d8) slots x 2 window-halves; uint4 V loads; shfl pair-combine
  if (tid < 192) {
    const int s = tid >> 1, half = tid & 1;
    const int h = s >> 3, dg = s & 7;
    const int j0 = i - (WINSZ - 1);
    const unsigned short* vcol = Vbase + h * HDIM + dg * 8;
    float a[8];
    #pragma unroll
    for (int c = 0; c < 8; c++) a[c] = 0.f;
    for (int n = 0; n < 64; n++) {
      int jw = half * 64 + n;
      float p = sc[h][jw];
      int j = j0 + jw;
      int jc = (j > 0) ? j : 0;          // p==0 exactly when j<0: product is 0
      uint4 u = *(const uint4*)(vcol + (size_t)jc * DIM);
      a[0] += p * bf2f(u.x & 0xffffu); a[1] += p * bf2f(u.x >> 16);
      a[2] += p * bf2f(u.y & 0xffffu); a[3] += p * bf2f(u.y >> 16);
      a[4] += p * bf2f(u.z & 0xffffu); a[5] += p * bf2f(u.z >> 16);
      a[6] += p * bf2f(u.w & 0xffffu); a[7] += p * bf2f(u.w >> 16);
    }
    #pragma unroll
    for (int c = 0; c < 8; c++) a[c] += __shfl_xor(a[c], 1);
    if (half == 0) {
      unsigned int r[4];
      #pragma unroll
      for (int c = 0; c < 4; c++) {
        bf16 b0 = __float2bfloat16(a[2*c]);
        bf16 b1 = __float2bfloat16(a[2*c+1]);
        r[c] = (unsigned int)(*(unsigned short*)&b0)
             | ((unsigned int)(*(unsigned short*)&b1) << 16);
      }
      uint4 o = {r[0], r[1], r[2], r[3]};
      *(uint4*)((unsigned short*)outp + (size_t)t * DIM + h * HDIM + dg * 8) = o;
    }
  }
}

// ---------------- fused silu(h1)*g, in place into h1 ----------------
__global__ void silumul_k(bf16* __restrict__ h1, const bf16* __restrict__ g) {
  size_t i = ((size_t)blockIdx.x * 256 + threadIdx.x) * 8;
  uint4 a = *(const uint4*)((const unsigned short*)h1 + i);
  uint4 bvec = *(const uint4*)((const unsigned short*)g + i);
  unsigned int au[4] = {a.x, a.y, a.z, a.w};
  unsigned int bu[4] = {bvec.x, bvec.y, bvec.z, bvec.w};
  unsigned int r[4];
  #pragma unroll
  for (int c = 0; c < 4; c++) {
    float h0 = bf2f(au[c] & 0xffffu), h1v = bf2f(au[c] >> 16);
    float g0 = bf2f(bu[c] & 0xffffu), g1 = bf2f(bu[c] >> 16);
    float r0 = h0 / (1.f + __expf(-h0)) * g0;
    float r1 = h1v / (1.f + __expf(-h1v)) * g1;
    bf16 b0 = __float2bfloat16(r0), b1 = __float2bfloat16(r1);
    unsigned short u0 = *(unsigned short*)&b0, u1 = *(unsigned short*)&b1;
    r[c] = (unsigned int)u0 | ((unsigned int)u1 << 16);
  }
  uint4 out = {r[0], r[1], r[2], r[3]};
  *(uint4*)((unsigned short*)h1 + i) = out;
}

extern "C" void kernel_launch(void* const* d_in, const int* in_sizes, int n_in,
                              void* d_out, int out_size, void* d_ws, size_t ws_size,
                              hipStream_t stream) {
  // Inputs fp32 (reference dtypes); internal pipeline bf16 MFMA; OUTPUT fp32.
  const float* x    = (const float*)d_in[0];
  const float* gate = (const float*)d_in[1];
  const float* q_w  = (const float*)d_in[2];
  const float* k_w  = (const float*)d_in[3];
  const float* v_w  = (const float*)d_in[4];
  const float* w1   = (const float*)d_in[5];
  const float* vg   = (const float*)d_in[6];
  const float* w2   = (const float*)d_in[7];
  const float* outw = (const float*)d_in[8];
  float* out = (float*)d_out;

  char* p = (char*)d_ws;
  auto alloc = [&](size_t bytes) {
    char* r = p;
    p += (bytes + 255) & ~(size_t)255;
    return r;
  };
  int*   ctrl = (int*)alloc(256);
  float* km   = (float*)alloc(16 * DIM * 4); // (e*2+b, d)
  int*   idxb = (int*)alloc(NTOK * 4);
  int*   perm = (int*)alloc(NTOK * 4);
  bf16* xb   = (bf16*)alloc((size_t)NTOK * DIM * 2);
  bf16* qwT  = (bf16*)alloc((size_t)NE * DIM * DIM * 2);
  bf16* kwT  = (bf16*)alloc((size_t)NE * DIM * DIM * 2);
  bf16* vwT  = (bf16*)alloc((size_t)NE * DIM * DIM * 2);
  bf16* w1T  = (bf16*)alloc((size_t)NE * DIM * FFN * 2);
  bf16* vgT  = (bf16*)alloc((size_t)NE * DIM * FFN * 2);
  bf16* w2T  = (bf16*)alloc((size_t)NE * FFN * DIM * 2);
  bf16* outT = (bf16*)alloc((size_t)DIM * DIM * 2);
  bf16* Kbuf = (bf16*)alloc((size_t)NE * NTOK * DIM * 2);
  bf16* Vbuf = (bf16*)alloc((size_t)NE * NTOK * DIM * 2);
  bf16* Qbuf = (bf16*)alloc((size_t)NTOK * DIM * 2);
  bf16* aout = (bf16*)alloc((size_t)NTOK * DIM * 2);
  // aliases over dead buffers (stream-serialized, safe):
  bf16* H1   = Kbuf;                                    // (NTOK, FFN) after attn
  bf16* Gb   = (bf16*)((char*)Kbuf + (size_t)NTOK * FFN * 2);
  bf16* Ybuf = Vbuf;                                    // (NTOK, DIM)

  int* cnt = ctrl;
  int* cursor = ctrl + 8;
  int* offs = ctrl + 16;
  float* psum = (float*)(ctrl + 32);

  hipMemsetAsync(d_ws, 0, 256 + 16 * DIM * 4, stream);  // ctrl + km

  cast_k<<<(NTOK * DIM / 8) / 256, 256, 0, stream>>>(x, xb);

  dim3 tb(32, 32);
  transpose_k<<<dim3(24, 24, 8), tb, 0, stream>>>(q_w, qwT, DIM, DIM);
  transpose_k<<<dim3(24, 24, 8), tb, 0, stream>>>(k_w, kwT, DIM, DIM);
  transpose_k<<<dim3(24, 24, 8), tb, 0, stream>>>(v_w, vwT, DIM, DIM);
  transpose_k<<<dim3(96, 24, 8), tb, 0, stream>>>(w1, w1T, DIM, FFN);
  transpose_k<<<dim3(96, 24, 8), tb, 0, stream>>>(vg, vgT, DIM, FFN);
  transpose_k<<<dim3(24, 96, 8), tb, 0, stream>>>(w2, w2T, FFN, DIM);
  transpose_k<<<dim3(24, 24, 1), tb, 0, stream>>>(outw, outT, DIM, DIM);

  router_k<<<NTOK, 64, 0, stream>>>(x, gate, idxb, cnt, psum);
  scan_k<<<1, 64, 0, stream>>>(cnt, psum, offs, out + (size_t)NTOK * DIM);
  scatter_k<<<NTOK / 256, 256, 0, stream>>>(idxb, offs, cursor, perm);

  // dense K/V projections: per expert (2048x768)@(768x768)
  gemm_bt<false, false, false, bf16><<<dim3(6, 16, 8), 256, 0, stream>>>(
      xb, kwT, (size_t)DIM * DIM, Kbuf, (size_t)NTOK * DIM, DIM, DIM, nullptr, nullptr);
  gemm_bt<false, false, false, bf16><<<dim3(6, 16, 8), 256, 0, stream>>>(
      xb, vwT, (size_t)DIM * DIM, Vbuf, (size_t)NTOK * DIM, DIM, DIM, nullptr, nullptr);
  kmean_k<<<dim3(3, 16, 8), 256, 0, stream>>>(Kbuf, km);

  // grouped Q projection (gather x rows, scatter to token order)
  gemm_bt<true, true, true, bf16><<<dim3(6, 16, 8), 256, 0, stream>>>(
      xb, qwT, (size_t)DIM * DIM, Qbuf, 0, DIM, DIM, offs, perm);

  attn_k<<<NTOK, 256, 0, stream>>>(Qbuf, Kbuf, Vbuf, km, idxb, aout);

  // grouped SwiGLU
  gemm_bt<true, true, false, bf16><<<dim3(24, 16, 8), 256, 0, stream>>>(
      aout, w1T, (size_t)DIM * FFN, H1, 0, FFN, DIM, offs, perm);
  gemm_bt<true, true, false, bf16><<<dim3(24, 16, 8), 256, 0, stream>>>(
      aout, vgT, (size_t)DIM * FFN, Gb, 0, FFN, DIM, offs, perm);
  silumul_k<<<(NTOK * FFN / 8) / 256, 256, 0, stream>>>(H1, Gb);
  gemm_bt<true, false, true, bf16><<<dim3(6, 16, 8), 256, 0, stream>>>(
      H1, w2T, (size_t)FFN * DIM, Ybuf, 0, DIM, FFN, offs, perm);

  // final projection -> d_out (fp32)
  gemm_bt<false, false, false, float><<<dim3(6, 16, 1), 256, 0, stream>>>(
      Ybuf, outT, 0, out, 0, DIM, DIM, nullptr, nullptr);
}

// Round 3
// 1208.375 us; speedup vs baseline: 1.3791x; 1.2102x over previous
//
#include <hip/hip_runtime.h>
#include <hip/hip_bf16.h>
#include <stdint.h>

typedef __hip_bfloat16 bf16;
typedef __attribute__((ext_vector_type(8))) short short8;
typedef __attribute__((ext_vector_type(4))) float f32x4;

#define NE 8
#define NH 12
#define HDIM 64
#define WINSZ 128
#define NB 2
#define SEQ 1024
#define DIM 768
#define FFN 3072
#define NTOK 2048   // NB*SEQ
#define SCP (WINSZ + 4)   // padded score stride
#define MAXSLOT 24  // max sum of ceil(cnt_e/128) = 7*1 + 16 = 23

__device__ __forceinline__ float bf2f(unsigned int u) {
  union { unsigned int i; float f; } v; v.i = u << 16; return v.f;
}

// ---------------- transpose + cast: in f32 (z, K, N) -> out bf16 (z, N, K) ----
__global__ void transpose_k(const float* __restrict__ in, bf16* __restrict__ out,
                            int K, int N) {
  __shared__ float s[32][33];
  const size_t zoff = (size_t)blockIdx.z * K * N;
  int n = blockIdx.x * 32 + threadIdx.x;
  int k = blockIdx.y * 32 + threadIdx.y;
  s[threadIdx.y][threadIdx.x] = in[zoff + (size_t)k * N + n];
  __syncthreads();
  int n2 = blockIdx.x * 32 + threadIdx.y;
  int k2 = blockIdx.y * 32 + threadIdx.x;
  out[zoff + (size_t)n2 * K + k2] = __float2bfloat16(s[threadIdx.x][threadIdx.y]);
}

// ---------------- cast f32 -> bf16, 8 elems/thread ----------------
__global__ void cast_k(const float* __restrict__ in, bf16* __restrict__ out) {
  size_t i = ((size_t)blockIdx.x * 256 + threadIdx.x) * 8;
  float4 a = *(const float4*)(in + i);
  float4 b = *(const float4*)(in + i + 4);
  unsigned short r[8];
  float v[8] = {a.x, a.y, a.z, a.w, b.x, b.y, b.z, b.w};
  #pragma unroll
  for (int c = 0; c < 8; c++) {
    bf16 t = __float2bfloat16(v[c]);
    r[c] = *(unsigned short*)&t;
  }
  uint4 o;
  o.x = r[0] | ((unsigned)r[1] << 16); o.y = r[2] | ((unsigned)r[3] << 16);
  o.z = r[4] | ((unsigned)r[5] << 16); o.w = r[6] | ((unsigned)r[7] << 16);
  *(uint4*)((unsigned short*)out + i) = o;
}

// ---------------- router (fp32 in): logits, softmax, argmax, stats ----------
__global__ void router_k(const float* __restrict__ x, const float* __restrict__ gw,
                         int* __restrict__ idx, int* __restrict__ cnt,
                         float* __restrict__ psum) {
  const int t = blockIdx.x;
  const int lane = threadIdx.x; // 64 threads
  const float* xr = x + (size_t)t * DIM;
  float acc[NE];
  #pragma unroll
  for (int e = 0; e < NE; e++) acc[e] = 0.f;
  for (int d = lane; d < DIM; d += 64) {
    float xv = xr[d];
    float4 g0 = *(const float4*)(gw + (size_t)d * NE);
    float4 g1 = *(const float4*)(gw + (size_t)d * NE + 4);
    acc[0] += xv * g0.x; acc[1] += xv * g0.y;
    acc[2] += xv * g0.z; acc[3] += xv * g0.w;
    acc[4] += xv * g1.x; acc[5] += xv * g1.y;
    acc[6] += xv * g1.z; acc[7] += xv * g1.w;
  }
  #pragma unroll
  for (int o = 32; o > 0; o >>= 1) {
    #pragma unroll
    for (int e = 0; e < NE; e++) acc[e] += __shfl_xor(acc[e], o, 64);
  }
  if (lane == 0) {
    float lg[NE];
    #pragma unroll
    for (int e = 0; e < NE; e++) lg[e] = acc[e] * 0.5f;  // TEMP=2.0
    float mx = lg[0]; int am = 0;
    #pragma unroll
    for (int e = 1; e < NE; e++) if (lg[e] > mx) { mx = lg[e]; am = e; }
    float s = 0.f, p[NE];
    #pragma unroll
    for (int e = 0; e < NE; e++) { p[e] = __expf(lg[e] - mx); s += p[e]; }
    float inv = 1.f / s;
    #pragma unroll
    for (int e = 0; e < NE; e++) atomicAdd(&psum[e], p[e] * inv);
    atomicAdd(&cnt[am], 1);
    idx[t] = am;
  }
}

// ---------------- scan offsets + slot table + aux loss ----------------
__global__ void scan_k(const int* __restrict__ cnt, const float* __restrict__ psum,
                       int* __restrict__ offs, int* __restrict__ eidx,
                       int* __restrict__ mb, float* __restrict__ aux_out) {
  if (threadIdx.x == 0 && blockIdx.x == 0) {
    int o = 0;
    for (int e = 0; e < NE; e++) { offs[e] = o; o += cnt[e]; }
    offs[NE] = o;
    int S = 0;
    for (int e = 0; e < NE; e++) {
      int nb = (cnt[e] + 127) >> 7;
      for (int k = 0; k < nb; k++) { eidx[S] = e; mb[S] = k * 128; S++; }
    }
    for (; S < MAXSLOT; S++) eidx[S] = -1;
    float aux = 0.f;
    for (int e = 0; e < NE; e++)
      aux += ((float)cnt[e] / (float)NTOK) * (psum[e] / (float)NTOK);
    aux_out[0] = aux * (float)NE;
  }
}

// ---------------- scatter tokens into per-expert groups ----------------
__global__ void scatter_k(const int* __restrict__ idx, const int* __restrict__ offs,
                          int* __restrict__ cursor, int* __restrict__ perm) {
  int t = blockIdx.x * 256 + threadIdx.x;
  if (t < NTOK) {
    int e = idx[t];
    int p = atomicAdd(&cursor[e], 1);
    perm[offs[e] + p] = t;
  }
}

// ---------------- K column-means per (expert,batch) ----------------
__global__ void kmean_k(const bf16* __restrict__ Kb, float* __restrict__ km) {
  int d = blockIdx.x * 256 + threadIdx.x;           // 0..767
  int z = blockIdx.y;                               // e*2+b
  int j0 = blockIdx.z * 128;
  const unsigned short* base = (const unsigned short*)Kb + (size_t)z * SEQ * DIM;
  float s = 0.f;
  for (int j = j0; j < j0 + 128; j++) s += bf2f(base[(size_t)j * DIM + d]);
  atomicAdd(&km[z * DIM + d], s * (1.f / (float)SEQ));
}

// ---------------- GEMM: C[M,N] = A[M,K] @ Bt[N,K]^T  (bf16 in, CT out, f32 acc) ----
// GROUPED path uses compacted slot table (eidx/mb) so active blocks are contiguous
// in blockIdx space -> spread across all CUs. K-loop prefetches next step's loads
// after the barrier so HBM latency overlaps MFMA.
template <bool GROUPED, bool GATHER, bool SCATTER, typename CT>
__global__ __launch_bounds__(256)
void gemm_bt(const bf16* __restrict__ A, const bf16* __restrict__ Bt, size_t Bstride,
             CT* __restrict__ C, size_t Cstride, int N, int K,
             const int* __restrict__ offs, const int* __restrict__ perm,
             const int* __restrict__ eidx, const int* __restrict__ mb) {
  __shared__ alignas(16) bf16 As[128 * 64];
  __shared__ alignas(16) bf16 Bs[128 * 64];
  const int tid = threadIdx.x;
  int ez, off = 0, cnt = NTOK, m_base;
  if constexpr (GROUPED) {
    int e = eidx[blockIdx.y];
    if (e < 0) return;
    ez = e; off = offs[e]; cnt = offs[e + 1] - off; m_base = mb[blockIdx.y];
  } else {
    ez = blockIdx.z; m_base = blockIdx.y * 128;
  }
  const int n_base = blockIdx.x * 128;
  const bf16* Be = Bt + (size_t)ez * Bstride;
  CT* Ce = C + (size_t)ez * Cstride;

  const bf16* aptr[4];
  const bf16* bptr[4];
  #pragma unroll
  for (int it = 0; it < 4; ++it) {
    int cid = it * 256 + tid;
    int row = cid >> 3, c8 = cid & 7;
    int r = m_base + row;
    int arow;
    if constexpr (GROUPED) {
      int rr = (r < cnt) ? r : (cnt - 1);
      arow = GATHER ? perm[off + rr] : (off + rr);
    } else {
      arow = r;
    }
    aptr[it] = A + (size_t)arow * K + c8 * 8;
    bptr[it] = Be + (size_t)(n_base + row) * K + c8 * 8;
  }

  f32x4 acc[4][4];
  #pragma unroll
  for (int i = 0; i < 4; i++)
    #pragma unroll
    for (int j = 0; j < 4; j++) acc[i][j] = {0.f, 0.f, 0.f, 0.f};

  const int lane = tid & 63;
  const int w = tid >> 6;
  const int wm = (w & 1) * 64, wn = (w >> 1) * 64;
  const int lrow = lane & 15;
  const int lk = (lane >> 4) * 8;

  uint4 av[4], bv[4];
  #pragma unroll
  for (int it = 0; it < 4; ++it) {
    av[it] = *(const uint4*)(aptr[it]);
    bv[it] = *(const uint4*)(bptr[it]);
  }

  for (int k0 = 0; k0 < K; k0 += 64) {
    __syncthreads();   // previous iteration's LDS reads complete before overwrite
    #pragma unroll
    for (int it = 0; it < 4; ++it) {
      *(uint4*)((char*)As + it * 4096 + tid * 16) = av[it];
      *(uint4*)((char*)Bs + it * 4096 + tid * 16) = bv[it];
    }
    __syncthreads();
    if (k0 + 64 < K) {
      #pragma unroll
      for (int it = 0; it < 4; ++it) {     // prefetch next step: overlaps MFMA
        av[it] = *(const uint4*)(aptr[it] + k0 + 64);
        bv[it] = *(const uint4*)(bptr[it] + k0 + 64);
      }
    }
    #pragma unroll
    for (int kk = 0; kk < 64; kk += 32) {
      short8 af[4], bfr[4];
      #pragma unroll
      for (int mt = 0; mt < 4; mt++)
        af[mt] = *(const short8*)&As[(wm + mt * 16 + lrow) * 64 + kk + lk];
      #pragma unroll
      for (int nt = 0; nt < 4; nt++)
        bfr[nt] = *(const short8*)&Bs[(wn + nt * 16 + lrow) * 64 + kk + lk];
      #pragma unroll
      for (int mt = 0; mt < 4; mt++)
        #pragma unroll
        for (int nt = 0; nt < 4; nt++)
          acc[mt][nt] = __builtin_amdgcn_mfma_f32_16x16x32_bf16(
              af[mt], bfr[nt], acc[mt][nt], 0, 0, 0);
    }
  }

  #pragma unroll
  for (int mt = 0; mt < 4; mt++) {
    #pragma unroll
    for (int r = 0; r < 4; r++) {
      int row_in = wm + mt * 16 + (lane >> 4) * 4 + r;
      int rr = m_base + row_in;
      if (GROUPED && rr >= cnt) continue;
      int crow;
      if constexpr (GROUPED) crow = SCATTER ? perm[off + rr] : (off + rr);
      else crow = rr;
      size_t base = (size_t)crow * N + n_base + wn + (lane & 15);
      #pragma unroll
      for (int nt = 0; nt < 4; nt++) {
        if constexpr (sizeof(CT) == 2)
          Ce[base + nt * 16] = __float2bfloat16(acc[mt][nt][r]);
        else
          Ce[base + nt * 16] = acc[mt][nt][r];
      }
    }
  }
}

// ---------------- dual-B GEMM: shared A-tile, two B streams ----------------
// EPI=0: C1 = A@B1^T, C2 = A@B2^T (both stored, bf16)  -> fused K,V projection
// EPI=1: C1 = silu(A@B1^T) * (A@B2^T)                  -> fused w1,vg,SwiGLU
template <bool GROUPED, bool GATHER, int EPI>
__global__ __launch_bounds__(256)
void gemm_bt2(const bf16* __restrict__ A, const bf16* __restrict__ B1t,
              const bf16* __restrict__ B2t, size_t Bstride,
              bf16* __restrict__ C1, bf16* __restrict__ C2, size_t Cstride,
              int N, int K,
              const int* __restrict__ offs, const int* __restrict__ perm,
              const int* __restrict__ eidx, const int* __restrict__ mb) {
  __shared__ alignas(16) bf16 As[128 * 64];
  __shared__ alignas(16) bf16 B1s[128 * 64];
  __shared__ alignas(16) bf16 B2s[128 * 64];
  const int tid = threadIdx.x;
  int ez, off = 0, cnt = NTOK, m_base;
  if constexpr (GROUPED) {
    int e = eidx[blockIdx.y];
    if (e < 0) return;
    ez = e; off = offs[e]; cnt = offs[e + 1] - off; m_base = mb[blockIdx.y];
  } else {
    ez = blockIdx.z; m_base = blockIdx.y * 128;
  }
  const int n_base = blockIdx.x * 128;
  const bf16* B1e = B1t + (size_t)ez * Bstride;
  const bf16* B2e = B2t + (size_t)ez * Bstride;
  bf16* C1e = C1 + (size_t)ez * Cstride;
  bf16* C2e = (EPI == 0) ? (C2 + (size_t)ez * Cstride) : nullptr;

  const bf16* aptr[4];
  const bf16* b1ptr[4];
  const bf16* b2ptr[4];
  #pragma unroll
  for (int it = 0; it < 4; ++it) {
    int cid = it * 256 + tid;
    int row = cid >> 3, c8 = cid & 7;
    int r = m_base + row;
    int arow;
    if constexpr (GROUPED) {
      int rr = (r < cnt) ? r : (cnt - 1);
      arow = GATHER ? perm[off + rr] : (off + rr);
    } else {
      arow = r;
    }
    aptr[it] = A + (size_t)arow * K + c8 * 8;
    b1ptr[it] = B1e + (size_t)(n_base + row) * K + c8 * 8;
    b2ptr[it] = B2e + (size_t)(n_base + row) * K + c8 * 8;
  }

  f32x4 acc1[4][4], acc2[4][4];
  #pragma unroll
  for (int i = 0; i < 4; i++)
    #pragma unroll
    for (int j = 0; j < 4; j++) {
      acc1[i][j] = {0.f, 0.f, 0.f, 0.f};
      acc2[i][j] = {0.f, 0.f, 0.f, 0.f};
    }

  const int lane = tid & 63;
  const int w = tid >> 6;
  const int wm = (w & 1) * 64, wn = (w >> 1) * 64;
  const int lrow = lane & 15;
  const int lk = (lane >> 4) * 8;

  for (int k0 = 0; k0 < K; k0 += 64) {
    uint4 av[4], b1v[4], b2v[4];
    #pragma unroll
    for (int it = 0; it < 4; ++it) {
      av[it] = *(const uint4*)(aptr[it] + k0);
      b1v[it] = *(const uint4*)(b1ptr[it] + k0);
      b2v[it] = *(const uint4*)(b2ptr[it] + k0);
    }
    __syncthreads();
    #pragma unroll
    for (int it = 0; it < 4; ++it) {
      *(uint4*)((char*)As + it * 4096 + tid * 16) = av[it];
      *(uint4*)((char*)B1s + it * 4096 + tid * 16) = b1v[it];
      *(uint4*)((char*)B2s + it * 4096 + tid * 16) = b2v[it];
    }
    __syncthreads();
    #pragma unroll
    for (int kk = 0; kk < 64; kk += 32) {
      short8 af[4], b1f[4], b2f[4];
      #pragma unroll
      for (int mt = 0; mt < 4; mt++)
        af[mt] = *(const short8*)&As[(wm + mt * 16 + lrow) * 64 + kk + lk];
      #pragma unroll
      for (int nt = 0; nt < 4; nt++) {
        b1f[nt] = *(const short8*)&B1s[(wn + nt * 16 + lrow) * 64 + kk + lk];
        b2f[nt] = *(const short8*)&B2s[(wn + nt * 16 + lrow) * 64 + kk + lk];
      }
      #pragma unroll
      for (int mt = 0; mt < 4; mt++)
        #pragma unroll
        for (int nt = 0; nt < 4; nt++) {
          acc1[mt][nt] = __builtin_amdgcn_mfma_f32_16x16x32_bf16(
              af[mt], b1f[nt], acc1[mt][nt], 0, 0, 0);
          acc2[mt][nt] = __builtin_amdgcn_mfma_f32_16x16x32_bf16(
              af[mt], b2f[nt], acc2[mt][nt], 0, 0, 0);
        }
    }
  }

  #pragma unroll
  for (int mt = 0; mt < 4; mt++) {
    #pragma unroll
    for (int r = 0; r < 4; r++) {
      int row_in = wm + mt * 16 + (lane >> 4) * 4 + r;
      int rr = m_base + row_in;
      if (GROUPED && rr >= cnt) continue;
      int crow;
      if constexpr (GROUPED) crow = off + rr;
      else crow = rr;
      size_t base = (size_t)crow * N + n_base + wn + (lane & 15);
      #pragma unroll
      for (int nt = 0; nt < 4; nt++) {
        if constexpr (EPI == 0) {
          C1e[base + nt * 16] = __float2bfloat16(acc1[mt][nt][r]);
          C2e[base + nt * 16] = __float2bfloat16(acc2[mt][nt][r]);
        } else {
          float v1 = acc1[mt][nt][r], v2 = acc2[mt][nt][r];
          float rv = v1 / (1.f + __expf(-v1)) * v2;
          C1e[base + nt * 16] = __float2bfloat16(rv);
        }
      }
    }
  }
}

// ---------------- sliding-window attention w/ reynolds modulation ----------------
__global__ __launch_bounds__(256)
void attn_k(const bf16* __restrict__ Q, const bf16* __restrict__ Kb,
            const bf16* __restrict__ Vb, const float* __restrict__ km,
            const int* __restrict__ idx, bf16* __restrict__ outp) {
  __shared__ alignas(16) float qf[DIM];
  __shared__ float means[NH];
  __shared__ float sc[NH][SCP];
  const int t = blockIdx.x;
  const int tid = threadIdx.x;
  const int b = t >> 10, i = t & (SEQ - 1);
  const int e = idx[t];
  const int z = e * 2 + b;
  const unsigned short* Kbase = (const unsigned short*)Kb + (size_t)z * SEQ * DIM;
  const unsigned short* Vbase = (const unsigned short*)Vb + (size_t)z * SEQ * DIM;
  const unsigned short* qrow = (const unsigned short*)Q + (size_t)t * DIM;

  for (int d = tid; d < DIM; d += 256) qf[d] = bf2f(qrow[d]);
  __syncthreads();

  if (tid < 192) {
    const int h = tid >> 4, l = tid & 15;
    float4 kv = *(const float4*)(km + (size_t)z * DIM + h * HDIM + l * 4);
    float4 qv = *(const float4*)(qf + h * HDIM + l * 4);
    float s = qv.x * kv.x + qv.y * kv.y + qv.z * kv.z + qv.w * kv.w;
    s += __shfl_xor(s, 1); s += __shfl_xor(s, 2);
    s += __shfl_xor(s, 4); s += __shfl_xor(s, 8);
    if (l == 0) means[h] = s * 0.125f;
  }
  __syncthreads();

  for (int slot = tid; slot < NH * WINSZ; slot += 256) {
    int h = slot >> 7, jw = slot & (WINSZ - 1);
    int j = i - (WINSZ - 1) + jw;
    float sv = -1e30f;
    if (j >= 0) {
      const uint4* kp = (const uint4*)(Kbase + (size_t)j * DIM + h * HDIM);
      const float* qh = qf + h * HDIM;
      float a = 0.f;
      #pragma unroll
      for (int c = 0; c < 8; c++) {
        uint4 u = kp[c];
        a += qh[c*8+0]*bf2f(u.x & 0xffffu) + qh[c*8+1]*bf2f(u.x >> 16)
           + qh[c*8+2]*bf2f(u.y & 0xffffu) + qh[c*8+3]*bf2f(u.y >> 16)
           + qh[c*8+4]*bf2f(u.z & 0xffffu) + qh[c*8+5]*bf2f(u.z >> 16)
           + qh[c*8+6]*bf2f(u.w & 0xffffu) + qh[c*8+7]*bf2f(u.w >> 16);
      }
      float s = a * 0.125f;
      float sig = 1.f / (1.f + __expf(-s));
      sv = 1.1f * s - 0.1f * sig * sig - 0.1f * fabsf(s - means[h]);
    }
    sc[h][jw] = sv;
  }
  __syncthreads();

  if (tid < 192) {
    const int h = tid >> 4, l = tid & 15;
    float vloc[8];
    float m = -1e30f;
    #pragma unroll
    for (int k = 0; k < 8; k++) {
      vloc[k] = sc[h][l + 16 * k];
      m = fmaxf(m, vloc[k]);
    }
    m = fmaxf(m, __shfl_xor(m, 1)); m = fmaxf(m, __shfl_xor(m, 2));
    m = fmaxf(m, __shfl_xor(m, 4)); m = fmaxf(m, __shfl_xor(m, 8));
    float ssum = 0.f;
    #pragma unroll
    for (int k = 0; k < 8; k++) {
      float ev = (vloc[k] > -1e29f) ? __expf(vloc[k] - m) : 0.f;
      vloc[k] = ev;
      ssum += ev;
    }
    ssum += __shfl_xor(ssum, 1); ssum += __shfl_xor(ssum, 2);
    ssum += __shfl_xor(ssum, 4); ssum += __shfl_xor(ssum, 8);
    float inv = 1.f / ssum;
    #pragma unroll
    for (int k = 0; k < 8; k++) sc[h][l + 16 * k] = vloc[k] * inv;
  }
  __syncthreads();

  if (tid < 192) {
    const int s = tid >> 1, half = tid & 1;
    const int h = s >> 3, dg = s & 7;
    const int j0 = i - (WINSZ - 1);
    const unsigned short* vcol = Vbase + h * HDIM + dg * 8;
    float a[8];
    #pragma unroll
    for (int c = 0; c < 8; c++) a[c] = 0.f;
    for (int n = 0; n < 64; n++) {
      int jw = half * 64 + n;
      float p = sc[h][jw];
      int j = j0 + jw;
      int jc = (j > 0) ? j : 0;          // p==0 exactly when j<0: product is 0
      uint4 u = *(const uint4*)(vcol + (size_t)jc * DIM);
      a[0] += p * bf2f(u.x & 0xffffu); a[1] += p * bf2f(u.x >> 16);
      a[2] += p * bf2f(u.y & 0xffffu); a[3] += p * bf2f(u.y >> 16);
      a[4] += p * bf2f(u.z & 0xffffu); a[5] += p * bf2f(u.z >> 16);
      a[6] += p * bf2f(u.w & 0xffffu); a[7] += p * bf2f(u.w >> 16);
    }
    #pragma unroll
    for (int c = 0; c < 8; c++) a[c] += __shfl_xor(a[c], 1);
    if (half == 0) {
      unsigned int r[4];
      #pragma unroll
      for (int c = 0; c < 4; c++) {
        bf16 b0 = __float2bfloat16(a[2*c]);
        bf16 b1 = __float2bfloat16(a[2*c+1]);
        r[c] = (unsigned int)(*(unsigned short*)&b0)
             | ((unsigned int)(*(unsigned short*)&b1) << 16);
      }
      uint4 o = {r[0], r[1], r[2], r[3]};
      *(uint4*)((unsigned short*)outp + (size_t)t * DIM + h * HDIM + dg * 8) = o;
    }
  }
}

extern "C" void kernel_launch(void* const* d_in, const int* in_sizes, int n_in,
                              void* d_out, int out_size, void* d_ws, size_t ws_size,
                              hipStream_t stream) {
  const float* x    = (const float*)d_in[0];
  const float* gate = (const float*)d_in[1];
  const float* q_w  = (const float*)d_in[2];
  const float* k_w  = (const float*)d_in[3];
  const float* v_w  = (const float*)d_in[4];
  const float* w1   = (const float*)d_in[5];
  const float* vg   = (const float*)d_in[6];
  const float* w2   = (const float*)d_in[7];
  const float* outw = (const float*)d_in[8];
  float* out = (float*)d_out;

  char* p = (char*)d_ws;
  auto alloc = [&](size_t bytes) {
    char* r = p;
    p += (bytes + 255) & ~(size_t)255;
    return r;
  };
  int*   ctrl = (int*)alloc(512);
  float* km   = (float*)alloc(16 * DIM * 4); // (e*2+b, d)
  int*   idxb = (int*)alloc(NTOK * 4);
  int*   perm = (int*)alloc(NTOK * 4);
  bf16* xb   = (bf16*)alloc((size_t)NTOK * DIM * 2);
  bf16* qwT  = (bf16*)alloc((size_t)NE * DIM * DIM * 2);
  bf16* kwT  = (bf16*)alloc((size_t)NE * DIM * DIM * 2);
  bf16* vwT  = (bf16*)alloc((size_t)NE * DIM * DIM * 2);
  bf16* w1T  = (bf16*)alloc((size_t)NE * DIM * FFN * 2);
  bf16* vgT  = (bf16*)alloc((size_t)NE * DIM * FFN * 2);
  bf16* w2T  = (bf16*)alloc((size_t)NE * FFN * DIM * 2);
  bf16* outT = (bf16*)alloc((size_t)DIM * DIM * 2);
  bf16* Kbuf = (bf16*)alloc((size_t)NE * NTOK * DIM * 2);
  bf16* Vbuf = (bf16*)alloc((size_t)NE * NTOK * DIM * 2);
  bf16* Qbuf = (bf16*)alloc((size_t)NTOK * DIM * 2);
  bf16* aout = (bf16*)alloc((size_t)NTOK * DIM * 2);
  // aliases over dead buffers (stream-serialized, safe):
  bf16* H1   = Kbuf;                                    // (NTOK, FFN) after attn
  bf16* Ybuf = Vbuf;                                    // (NTOK, DIM)

  int* cnt    = ctrl;            // 8
  int* cursor = ctrl + 8;        // 8
  int* offs   = ctrl + 16;       // 9
  int* eidx   = ctrl + 32;       // 24
  int* mb     = ctrl + 56;       // 24
  float* psum = (float*)(ctrl + 80); // 8

  hipMemsetAsync(d_ws, 0, 512 + 16 * DIM * 4, stream);  // ctrl + km

  cast_k<<<(NTOK * DIM / 8) / 256, 256, 0, stream>>>(x, xb);

  dim3 tb(32, 32);
  transpose_k<<<dim3(24, 24, 8), tb, 0, stream>>>(q_w, qwT, DIM, DIM);
  transpose_k<<<dim3(24, 24, 8), tb, 0, stream>>>(k_w, kwT, DIM, DIM);
  transpose_k<<<dim3(24, 24, 8), tb, 0, stream>>>(v_w, vwT, DIM, DIM);
  transpose_k<<<dim3(96, 24, 8), tb, 0, stream>>>(w1, w1T, DIM, FFN);
  transpose_k<<<dim3(96, 24, 8), tb, 0, stream>>>(vg, vgT, DIM, FFN);
  transpose_k<<<dim3(24, 96, 8), tb, 0, stream>>>(w2, w2T, FFN, DIM);
  transpose_k<<<dim3(24, 24, 1), tb, 0, stream>>>(outw, outT, DIM, DIM);

  router_k<<<NTOK, 64, 0, stream>>>(x, gate, idxb, cnt, psum);
  scan_k<<<1, 64, 0, stream>>>(cnt, psum, offs, eidx, mb, out + (size_t)NTOK * DIM);
  scatter_k<<<NTOK / 256, 256, 0, stream>>>(idxb, offs, cursor, perm);

  // fused dense K+V projections: per expert (2048x768)@(768x768) x2
  gemm_bt2<false, false, 0><<<dim3(6, 16, 8), 256, 0, stream>>>(
      xb, kwT, vwT, (size_t)DIM * DIM, Kbuf, Vbuf, (size_t)NTOK * DIM, DIM, DIM,
      nullptr, nullptr, nullptr, nullptr);
  kmean_k<<<dim3(3, 16, 8), 256, 0, stream>>>(Kbuf, km);

  // grouped Q projection (gather x rows, scatter to token order), slot-compacted
  gemm_bt<true, true, true, bf16><<<dim3(6, MAXSLOT, 1), 256, 0, stream>>>(
      xb, qwT, (size_t)DIM * DIM, Qbuf, 0, DIM, DIM, offs, perm, eidx, mb);

  attn_k<<<NTOK, 256, 0, stream>>>(Qbuf, Kbuf, Vbuf, km, idxb, aout);

  // fused grouped SwiGLU up-projection: H1 = silu(aout@w1T)*(aout@vgT)
  gemm_bt2<true, true, 1><<<dim3(24, MAXSLOT, 1), 256, 0, stream>>>(
      aout, w1T, vgT, (size_t)DIM * FFN, H1, nullptr, 0, FFN, DIM,
      offs, perm, eidx, mb);

  // grouped down-projection, scatter back to token order
  gemm_bt<true, false, true, bf16><<<dim3(6, MAXSLOT, 1), 256, 0, stream>>>(
      H1, w2T, (size_t)FFN * DIM, Ybuf, 0, DIM, FFN, offs, perm, eidx, mb);

  // final projection -> d_out (fp32)
  gemm_bt<false, false, false, float><<<dim3(6, 16, 1), 256, 0, stream>>>(
      Ybuf, outT, 0, out, 0, DIM, DIM, nullptr, nullptr, nullptr, nullptr);
}

// Round 5
// 997.534 us; speedup vs baseline: 1.6706x; 1.2114x over previous
//
#include <hip/hip_runtime.h>
#include <hip/hip_bf16.h>
#include <stdint.h>

typedef __hip_bfloat16 bf16;
typedef __attribute__((ext_vector_type(8))) short short8;
typedef __attribute__((ext_vector_type(4))) float f32x4;

#define NE 8
#define NH 12
#define HDIM 64
#define WINSZ 128
#define NB 2
#define SEQ 1024
#define DIM 768
#define FFN 3072
#define NTOK 2048   // NB*SEQ
#define SCP (WINSZ + 4)   // padded score stride
#define MAXSLOT 24  // max sum of ceil(cnt_e/128) = 7*1 + 16 = 23

__device__ __forceinline__ float bf2f(unsigned int u) {
  union { unsigned int i; float f; } v; v.i = u << 16; return v.f;
}

// ---------------- transpose + cast: in f32 (z, K, N) -> out bf16 (z, N, K) ----
__global__ void transpose_k(const float* __restrict__ in, bf16* __restrict__ out,
                            int K, int N) {
  __shared__ float s[32][33];
  const size_t zoff = (size_t)blockIdx.z * K * N;
  int n = blockIdx.x * 32 + threadIdx.x;
  int k = blockIdx.y * 32 + threadIdx.y;
  s[threadIdx.y][threadIdx.x] = in[zoff + (size_t)k * N + n];
  __syncthreads();
  int n2 = blockIdx.x * 32 + threadIdx.y;
  int k2 = blockIdx.y * 32 + threadIdx.x;
  out[zoff + (size_t)n2 * K + k2] = __float2bfloat16(s[threadIdx.x][threadIdx.y]);
}

// ---------------- cast f32 -> bf16, 8 elems/thread ----------------
__global__ void cast_k(const float* __restrict__ in, bf16* __restrict__ out) {
  size_t i = ((size_t)blockIdx.x * 256 + threadIdx.x) * 8;
  float4 a = *(const float4*)(in + i);
  float4 b = *(const float4*)(in + i + 4);
  unsigned short r[8];
  float v[8] = {a.x, a.y, a.z, a.w, b.x, b.y, b.z, b.w};
  #pragma unroll
  for (int c = 0; c < 8; c++) {
    bf16 t = __float2bfloat16(v[c]);
    r[c] = *(unsigned short*)&t;
  }
  uint4 o;
  o.x = r[0] | ((unsigned)r[1] << 16); o.y = r[2] | ((unsigned)r[3] << 16);
  o.z = r[4] | ((unsigned)r[5] << 16); o.w = r[6] | ((unsigned)r[7] << 16);
  *(uint4*)((unsigned short*)out + i) = o;
}

// ---------------- router: logits, softmax, argmax -> probs buffer (NO atomics) ----
__global__ void router_k(const float* __restrict__ x, const float* __restrict__ gw,
                         int* __restrict__ idx, float* __restrict__ probs) {
  const int t = blockIdx.x;
  const int lane = threadIdx.x; // 64 threads
  const float* xr = x + (size_t)t * DIM;
  float acc[NE];
  #pragma unroll
  for (int e = 0; e < NE; e++) acc[e] = 0.f;
  for (int d = lane; d < DIM; d += 64) {
    float xv = xr[d];
    float4 g0 = *(const float4*)(gw + (size_t)d * NE);
    float4 g1 = *(const float4*)(gw + (size_t)d * NE + 4);
    acc[0] += xv * g0.x; acc[1] += xv * g0.y;
    acc[2] += xv * g0.z; acc[3] += xv * g0.w;
    acc[4] += xv * g1.x; acc[5] += xv * g1.y;
    acc[6] += xv * g1.z; acc[7] += xv * g1.w;
  }
  #pragma unroll
  for (int o = 32; o > 0; o >>= 1) {
    #pragma unroll
    for (int e = 0; e < NE; e++) acc[e] += __shfl_xor(acc[e], o, 64);
  }
  if (lane == 0) {
    float lg[NE];
    #pragma unroll
    for (int e = 0; e < NE; e++) lg[e] = acc[e] * 0.5f;  // TEMP=2.0
    float mx = lg[0]; int am = 0;
    #pragma unroll
    for (int e = 1; e < NE; e++) if (lg[e] > mx) { mx = lg[e]; am = e; }
    float s = 0.f, p[NE];
    #pragma unroll
    for (int e = 0; e < NE; e++) { p[e] = __expf(lg[e] - mx); s += p[e]; }
    float inv = 1.f / s;
    float4 p0 = {p[0] * inv, p[1] * inv, p[2] * inv, p[3] * inv};
    float4 p1 = {p[4] * inv, p[5] * inv, p[6] * inv, p[7] * inv};
    *(float4*)(probs + (size_t)t * NE) = p0;
    *(float4*)(probs + (size_t)t * NE + 4) = p1;
    idx[t] = am;
  }
}

// ---------------- reduce probs/idx -> cnt, psum; offsets + slot table + aux ----
__global__ void scan_k(const int* __restrict__ idx, const float* __restrict__ probs,
                       int* __restrict__ offs, int* __restrict__ eidx,
                       int* __restrict__ mb, float* __restrict__ aux_out) {
  __shared__ float psum_s[NE];
  __shared__ int cnt_s[NE];
  const int tid = threadIdx.x;   // 256 threads, 1 block
  const int lane = tid & 63;
  if (tid < NE) { psum_s[tid] = 0.f; cnt_s[tid] = 0; }
  __syncthreads();
  float ps[NE];
  int cs[NE];
  #pragma unroll
  for (int e = 0; e < NE; e++) { ps[e] = 0.f; cs[e] = 0; }
  for (int t = tid; t < NTOK; t += 256) {
    float4 p0 = *(const float4*)(probs + (size_t)t * NE);
    float4 p1 = *(const float4*)(probs + (size_t)t * NE + 4);
    ps[0] += p0.x; ps[1] += p0.y; ps[2] += p0.z; ps[3] += p0.w;
    ps[4] += p1.x; ps[5] += p1.y; ps[6] += p1.z; ps[7] += p1.w;
    cs[idx[t]]++;
  }
  #pragma unroll
  for (int o = 32; o > 0; o >>= 1) {
    #pragma unroll
    for (int e = 0; e < NE; e++) {
      ps[e] += __shfl_xor(ps[e], o, 64);
      cs[e] += __shfl_xor(cs[e], o, 64);
    }
  }
  if (lane == 0) {
    #pragma unroll
    for (int e = 0; e < NE; e++) {
      atomicAdd(&psum_s[e], ps[e]);
      atomicAdd(&cnt_s[e], cs[e]);
    }
  }
  __syncthreads();
  if (tid == 0) {
    int o = 0;
    for (int e = 0; e < NE; e++) { offs[e] = o; o += cnt_s[e]; }
    offs[NE] = o;
    int S = 0;
    for (int e = 0; e < NE; e++) {
      int nb = (cnt_s[e] + 127) >> 7;
      for (int k = 0; k < nb; k++) { eidx[S] = e; mb[S] = k * 128; S++; }
    }
    for (; S < MAXSLOT; S++) eidx[S] = -1;
    float aux = 0.f;
    for (int e = 0; e < NE; e++)
      aux += ((float)cnt_s[e] / (float)NTOK) * (psum_s[e] / (float)NTOK);
    aux_out[0] = aux * (float)NE;
  }
}

// ---------------- scatter tokens into per-expert groups (ballot-aggregated) ----
__global__ void scatter_k(const int* __restrict__ idx, const int* __restrict__ offs,
                          int* __restrict__ cursor, int* __restrict__ perm) {
  int t = blockIdx.x * 256 + threadIdx.x;
  int lane = threadIdx.x & 63;
  int e = idx[t];
  int myrank = 0;
  #pragma unroll
  for (int e0 = 0; e0 < NE; e0++) {
    unsigned long long m = __ballot(e == e0);
    if (m) {
      int leader = __ffsll((long long)m) - 1;
      int base = 0;
      if (lane == leader) base = atomicAdd(&cursor[e0], __popcll(m));
      base = __shfl(base, leader, 64);
      if (e == e0) myrank = base + __popcll(m & ((1ull << lane) - 1ull));
    }
  }
  perm[offs[e] + myrank] = t;
}

// ---------------- K column-means per (expert,batch) ----------------
__global__ void kmean_k(const bf16* __restrict__ Kb, float* __restrict__ km) {
  int d = blockIdx.x * 256 + threadIdx.x;           // 0..767
  int z = blockIdx.y;                               // e*2+b
  int j0 = blockIdx.z * 128;
  const unsigned short* base = (const unsigned short*)Kb + (size_t)z * SEQ * DIM;
  float s = 0.f;
  for (int j = j0; j < j0 + 128; j++) s += bf2f(base[(size_t)j * DIM + d]);
  atomicAdd(&km[z * DIM + d], s * (1.f / (float)SEQ));
}

// ---------------- GEMM: C[M,N] = A[M,K] @ Bt[N,K]^T  (bf16 in, CT out, f32 acc) ----
template <bool GROUPED, bool GATHER, bool SCATTER, typename CT>
__global__ __launch_bounds__(256)
void gemm_bt(const bf16* __restrict__ A, const bf16* __restrict__ Bt, size_t Bstride,
             CT* __restrict__ C, size_t Cstride, int N, int K,
             const int* __restrict__ offs, const int* __restrict__ perm,
             const int* __restrict__ eidx, const int* __restrict__ mb) {
  __shared__ alignas(16) bf16 As[128 * 64];
  __shared__ alignas(16) bf16 Bs[128 * 64];
  const int tid = threadIdx.x;
  int ez, off = 0, cnt = NTOK, m_base;
  if constexpr (GROUPED) {
    int e = eidx[blockIdx.y];
    if (e < 0) return;
    ez = e; off = offs[e]; cnt = offs[e + 1] - off; m_base = mb[blockIdx.y];
  } else {
    ez = blockIdx.z; m_base = blockIdx.y * 128;
  }
  const int n_base = blockIdx.x * 128;
  const bf16* Be = Bt + (size_t)ez * Bstride;
  CT* Ce = C + (size_t)ez * Cstride;

  const bf16* aptr[4];
  const bf16* bptr[4];
  #pragma unroll
  for (int it = 0; it < 4; ++it) {
    int cid = it * 256 + tid;
    int row = cid >> 3, c8 = cid & 7;
    int r = m_base + row;
    int arow;
    if constexpr (GROUPED) {
      int rr = (r < cnt) ? r : (cnt - 1);
      arow = GATHER ? perm[off + rr] : (off + rr);
    } else {
      arow = r;
    }
    aptr[it] = A + (size_t)arow * K + c8 * 8;
    bptr[it] = Be + (size_t)(n_base + row) * K + c8 * 8;
  }

  f32x4 acc[4][4];
  #pragma unroll
  for (int i = 0; i < 4; i++)
    #pragma unroll
    for (int j = 0; j < 4; j++) acc[i][j] = {0.f, 0.f, 0.f, 0.f};

  const int lane = tid & 63;
  const int w = tid >> 6;
  const int wm = (w & 1) * 64, wn = (w >> 1) * 64;
  const int lrow = lane & 15;
  const int lk = (lane >> 4) * 8;

  uint4 av[4], bv[4];
  #pragma unroll
  for (int it = 0; it < 4; ++it) {
    av[it] = *(const uint4*)(aptr[it]);
    bv[it] = *(const uint4*)(bptr[it]);
  }

  for (int k0 = 0; k0 < K; k0 += 64) {
    __syncthreads();   // previous iteration's LDS reads complete before overwrite
    #pragma unroll
    for (int it = 0; it < 4; ++it) {
      *(uint4*)((char*)As + it * 4096 + tid * 16) = av[it];
      *(uint4*)((char*)Bs + it * 4096 + tid * 16) = bv[it];
    }
    __syncthreads();
    if (k0 + 64 < K) {
      #pragma unroll
      for (int it = 0; it < 4; ++it) {     // prefetch next step: overlaps MFMA
        av[it] = *(const uint4*)(aptr[it] + k0 + 64);
        bv[it] = *(const uint4*)(bptr[it] + k0 + 64);
      }
    }
    #pragma unroll
    for (int kk = 0; kk < 64; kk += 32) {
      short8 af[4], bfr[4];
      #pragma unroll
      for (int mt = 0; mt < 4; mt++)
        af[mt] = *(const short8*)&As[(wm + mt * 16 + lrow) * 64 + kk + lk];
      #pragma unroll
      for (int nt = 0; nt < 4; nt++)
        bfr[nt] = *(const short8*)&Bs[(wn + nt * 16 + lrow) * 64 + kk + lk];
      #pragma unroll
      for (int mt = 0; mt < 4; mt++)
        #pragma unroll
        for (int nt = 0; nt < 4; nt++)
          acc[mt][nt] = __builtin_amdgcn_mfma_f32_16x16x32_bf16(
              af[mt], bfr[nt], acc[mt][nt], 0, 0, 0);
    }
  }

  #pragma unroll
  for (int mt = 0; mt < 4; mt++) {
    #pragma unroll
    for (int r = 0; r < 4; r++) {
      int row_in = wm + mt * 16 + (lane >> 4) * 4 + r;
      int rr = m_base + row_in;
      if (GROUPED && rr >= cnt) continue;
      int crow;
      if constexpr (GROUPED) crow = SCATTER ? perm[off + rr] : (off + rr);
      else crow = rr;
      size_t base = (size_t)crow * N + n_base + wn + (lane & 15);
      #pragma unroll
      for (int nt = 0; nt < 4; nt++) {
        if constexpr (sizeof(CT) == 2)
          Ce[base + nt * 16] = __float2bfloat16(acc[mt][nt][r]);
        else
          Ce[base + nt * 16] = acc[mt][nt][r];
      }
    }
  }
}

// ---------------- dual-B GEMM: shared A-tile, two B streams ----------------
// EPI=0: C1 = A@B1^T, C2 = A@B2^T (both stored, bf16)  -> fused K,V projection
// EPI=1: C1 = silu(A@B1^T) * (A@B2^T)                  -> fused w1,vg,SwiGLU
template <bool GROUPED, bool GATHER, int EPI>
__global__ __launch_bounds__(256)
void gemm_bt2(const bf16* __restrict__ A, const bf16* __restrict__ B1t,
              const bf16* __restrict__ B2t, size_t Bstride,
              bf16* __restrict__ C1, bf16* __restrict__ C2, size_t Cstride,
              int N, int K,
              const int* __restrict__ offs, const int* __restrict__ perm,
              const int* __restrict__ eidx, const int* __restrict__ mb) {
  __shared__ alignas(16) bf16 As[128 * 64];
  __shared__ alignas(16) bf16 B1s[128 * 64];
  __shared__ alignas(16) bf16 B2s[128 * 64];
  const int tid = threadIdx.x;
  int ez, off = 0, cnt = NTOK, m_base;
  if constexpr (GROUPED) {
    int e = eidx[blockIdx.y];
    if (e < 0) return;
    ez = e; off = offs[e]; cnt = offs[e + 1] - off; m_base = mb[blockIdx.y];
  } else {
    ez = blockIdx.z; m_base = blockIdx.y * 128;
  }
  const int n_base = blockIdx.x * 128;
  const bf16* B1e = B1t + (size_t)ez * Bstride;
  const bf16* B2e = B2t + (size_t)ez * Bstride;
  bf16* C1e = C1 + (size_t)ez * Cstride;
  bf16* C2e = (EPI == 0) ? (C2 + (size_t)ez * Cstride) : nullptr;

  const bf16* aptr[4];
  const bf16* b1ptr[4];
  const bf16* b2ptr[4];
  #pragma unroll
  for (int it = 0; it < 4; ++it) {
    int cid = it * 256 + tid;
    int row = cid >> 3, c8 = cid & 7;
    int r = m_base + row;
    int arow;
    if constexpr (GROUPED) {
      int rr = (r < cnt) ? r : (cnt - 1);
      arow = GATHER ? perm[off + rr] : (off + rr);
    } else {
      arow = r;
    }
    aptr[it] = A + (size_t)arow * K + c8 * 8;
    b1ptr[it] = B1e + (size_t)(n_base + row) * K + c8 * 8;
    b2ptr[it] = B2e + (size_t)(n_base + row) * K + c8 * 8;
  }

  f32x4 acc1[4][4], acc2[4][4];
  #pragma unroll
  for (int i = 0; i < 4; i++)
    #pragma unroll
    for (int j = 0; j < 4; j++) {
      acc1[i][j] = {0.f, 0.f, 0.f, 0.f};
      acc2[i][j] = {0.f, 0.f, 0.f, 0.f};
    }

  const int lane = tid & 63;
  const int w = tid >> 6;
  const int wm = (w & 1) * 64, wn = (w >> 1) * 64;
  const int lrow = lane & 15;
  const int lk = (lane >> 4) * 8;

  for (int k0 = 0; k0 < K; k0 += 64) {
    uint4 av[4], b1v[4], b2v[4];
    #pragma unroll
    for (int it = 0; it < 4; ++it) {
      av[it] = *(const uint4*)(aptr[it] + k0);
      b1v[it] = *(const uint4*)(b1ptr[it] + k0);
      b2v[it] = *(const uint4*)(b2ptr[it] + k0);
    }
    __syncthreads();
    #pragma unroll
    for (int it = 0; it < 4; ++it) {
      *(uint4*)((char*)As + it * 4096 + tid * 16) = av[it];
      *(uint4*)((char*)B1s + it * 4096 + tid * 16) = b1v[it];
      *(uint4*)((char*)B2s + it * 4096 + tid * 16) = b2v[it];
    }
    __syncthreads();
    #pragma unroll
    for (int kk = 0; kk < 64; kk += 32) {
      short8 af[4], b1f[4], b2f[4];
      #pragma unroll
      for (int mt = 0; mt < 4; mt++)
        af[mt] = *(const short8*)&As[(wm + mt * 16 + lrow) * 64 + kk + lk];
      #pragma unroll
      for (int nt = 0; nt < 4; nt++) {
        b1f[nt] = *(const short8*)&B1s[(wn + nt * 16 + lrow) * 64 + kk + lk];
        b2f[nt] = *(const short8*)&B2s[(wn + nt * 16 + lrow) * 64 + kk + lk];
      }
      #pragma unroll
      for (int mt = 0; mt < 4; mt++)
        #pragma unroll
        for (int nt = 0; nt < 4; nt++) {
          acc1[mt][nt] = __builtin_amdgcn_mfma_f32_16x16x32_bf16(
              af[mt], b1f[nt], acc1[mt][nt], 0, 0, 0);
          acc2[mt][nt] = __builtin_amdgcn_mfma_f32_16x16x32_bf16(
              af[mt], b2f[nt], acc2[mt][nt], 0, 0, 0);
        }
    }
  }

  #pragma unroll
  for (int mt = 0; mt < 4; mt++) {
    #pragma unroll
    for (int r = 0; r < 4; r++) {
      int row_in = wm + mt * 16 + (lane >> 4) * 4 + r;
      int rr = m_base + row_in;
      if (GROUPED && rr >= cnt) continue;
      int crow;
      if constexpr (GROUPED) crow = off + rr;
      else crow = rr;
      size_t base = (size_t)crow * N + n_base + wn + (lane & 15);
      #pragma unroll
      for (int nt = 0; nt < 4; nt++) {
        if constexpr (EPI == 0) {
          C1e[base + nt * 16] = __float2bfloat16(acc1[mt][nt][r]);
          C2e[base + nt * 16] = __float2bfloat16(acc2[mt][nt][r]);
        } else {
          float v1 = acc1[mt][nt][r], v2 = acc2[mt][nt][r];
          float rv = v1 / (1.f + __expf(-v1)) * v2;
          C1e[base + nt * 16] = __float2bfloat16(rv);
        }
      }
    }
  }
}

// ---------------- sliding-window attention w/ reynolds modulation ----------------
__global__ __launch_bounds__(256)
void attn_k(const bf16* __restrict__ Q, const bf16* __restrict__ Kb,
            const bf16* __restrict__ Vb, const float* __restrict__ km,
            const int* __restrict__ idx, bf16* __restrict__ outp) {
  __shared__ alignas(16) float qf[DIM];
  __shared__ float means[NH];
  __shared__ float sc[NH][SCP];
  const int t = blockIdx.x;
  const int tid = threadIdx.x;
  const int b = t >> 10, i = t & (SEQ - 1);
  const int e = idx[t];
  const int z = e * 2 + b;
  const unsigned short* Kbase = (const unsigned short*)Kb + (size_t)z * SEQ * DIM;
  const unsigned short* Vbase = (const unsigned short*)Vb + (size_t)z * SEQ * DIM;
  const unsigned short* qrow = (const unsigned short*)Q + (size_t)t * DIM;

  for (int d = tid; d < DIM; d += 256) qf[d] = bf2f(qrow[d]);
  __syncthreads();

  if (tid < 192) {
    const int h = tid >> 4, l = tid & 15;
    float4 kv = *(const float4*)(km + (size_t)z * DIM + h * HDIM + l * 4);
    float4 qv = *(const float4*)(qf + h * HDIM + l * 4);
    float s = qv.x * kv.x + qv.y * kv.y + qv.z * kv.z + qv.w * kv.w;
    s += __shfl_xor(s, 1); s += __shfl_xor(s, 2);
    s += __shfl_xor(s, 4); s += __shfl_xor(s, 8);
    if (l == 0) means[h] = s * 0.125f;
  }
  __syncthreads();

  for (int slot = tid; slot < NH * WINSZ; slot += 256) {
    int h = slot >> 7, jw = slot & (WINSZ - 1);
    int j = i - (WINSZ - 1) + jw;
    float sv = -1e30f;
    if (j >= 0) {
      const uint4* kp = (const uint4*)(Kbase + (size_t)j * DIM + h * HDIM);
      const float* qh = qf + h * HDIM;
      float a = 0.f;
      #pragma unroll
      for (int c = 0; c < 8; c++) {
        uint4 u = kp[c];
        a += qh[c*8+0]*bf2f(u.x & 0xffffu) + qh[c*8+1]*bf2f(u.x >> 16)
           + qh[c*8+2]*bf2f(u.y & 0xffffu) + qh[c*8+3]*bf2f(u.y >> 16)
           + qh[c*8+4]*bf2f(u.z & 0xffffu) + qh[c*8+5]*bf2f(u.z >> 16)
           + qh[c*8+6]*bf2f(u.w & 0xffffu) + qh[c*8+7]*bf2f(u.w >> 16);
      }
      float s = a * 0.125f;
      float sig = 1.f / (1.f + __expf(-s));
      sv = 1.1f * s - 0.1f * sig * sig - 0.1f * fabsf(s - means[h]);
    }
    sc[h][jw] = sv;
  }
  __syncthreads();

  if (tid < 192) {
    const int h = tid >> 4, l = tid & 15;
    float vloc[8];
    float m = -1e30f;
    #pragma unroll
    for (int k = 0; k < 8; k++) {
      vloc[k] = sc[h][l + 16 * k];
      m = fmaxf(m, vloc[k]);
    }
    m = fmaxf(m, __shfl_xor(m, 1)); m = fmaxf(m, __shfl_xor(m, 2));
    m = fmaxf(m, __shfl_xor(m, 4)); m = fmaxf(m, __shfl_xor(m, 8));
    float ssum = 0.f;
    #pragma unroll
    for (int k = 0; k < 8; k++) {
      float ev = (vloc[k] > -1e29f) ? __expf(vloc[k] - m) : 0.f;
      vloc[k] = ev;
      ssum += ev;
    }
    ssum += __shfl_xor(ssum, 1); ssum += __shfl_xor(ssum, 2);
    ssum += __shfl_xor(ssum, 4); ssum += __shfl_xor(ssum, 8);
    float inv = 1.f / ssum;
    #pragma unroll
    for (int k = 0; k < 8; k++) sc[h][l + 16 * k] = vloc[k] * inv;
  }
  __syncthreads();

  if (tid < 192) {
    const int s = tid >> 1, half = tid & 1;
    const int h = s >> 3, dg = s & 7;
    const int j0 = i - (WINSZ - 1);
    const unsigned short* vcol = Vbase + h * HDIM + dg * 8;
    float a[8];
    #pragma unroll
    for (int c = 0; c < 8; c++) a[c] = 0.f;
    for (int n = 0; n < 64; n++) {
      int jw = half * 64 + n;
      float p = sc[h][jw];
      int j = j0 + jw;
      int jc = (j > 0) ? j : 0;          // p==0 exactly when j<0: product is 0
      uint4 u = *(const uint4*)(vcol + (size_t)jc * DIM);
      a[0] += p * bf2f(u.x & 0xffffu); a[1] += p * bf2f(u.x >> 16);
      a[2] += p * bf2f(u.y & 0xffffu); a[3] += p * bf2f(u.y >> 16);
      a[4] += p * bf2f(u.z & 0xffffu); a[5] += p * bf2f(u.z >> 16);
      a[6] += p * bf2f(u.w & 0xffffu); a[7] += p * bf2f(u.w >> 16);
    }
    #pragma unroll
    for (int c = 0; c < 8; c++) a[c] += __shfl_xor(a[c], 1);
    if (half == 0) {
      unsigned int r[4];
      #pragma unroll
      for (int c = 0; c < 4; c++) {
        bf16 b0 = __float2bfloat16(a[2*c]);
        bf16 b1 = __float2bfloat16(a[2*c+1]);
        r[c] = (unsigned int)(*(unsigned short*)&b0)
             | ((unsigned int)(*(unsigned short*)&b1) << 16);
      }
      uint4 o = {r[0], r[1], r[2], r[3]};
      *(uint4*)((unsigned short*)outp + (size_t)t * DIM + h * HDIM + dg * 8) = o;
    }
  }
}

extern "C" void kernel_launch(void* const* d_in, const int* in_sizes, int n_in,
                              void* d_out, int out_size, void* d_ws, size_t ws_size,
                              hipStream_t stream) {
  const float* x    = (const float*)d_in[0];
  const float* gate = (const float*)d_in[1];
  const float* q_w  = (const float*)d_in[2];
  const float* k_w  = (const float*)d_in[3];
  const float* v_w  = (const float*)d_in[4];
  const float* w1   = (const float*)d_in[5];
  const float* vg   = (const float*)d_in[6];
  const float* w2   = (const float*)d_in[7];
  const float* outw = (const float*)d_in[8];
  float* out = (float*)d_out;

  char* p = (char*)d_ws;
  auto alloc = [&](size_t bytes) {
    char* r = p;
    p += (bytes + 255) & ~(size_t)255;
    return r;
  };
  int*   ctrl  = (int*)alloc(512);
  float* km    = (float*)alloc(16 * DIM * 4); // (e*2+b, d)
  int*   idxb  = (int*)alloc(NTOK * 4);
  int*   perm  = (int*)alloc(NTOK * 4);
  float* probs = (float*)alloc((size_t)NTOK * NE * 4);
  bf16* xb   = (bf16*)alloc((size_t)NTOK * DIM * 2);
  bf16* qwT  = (bf16*)alloc((size_t)NE * DIM * DIM * 2);
  bf16* kwT  = (bf16*)alloc((size_t)NE * DIM * DIM * 2);
  bf16* vwT  = (bf16*)alloc((size_t)NE * DIM * DIM * 2);
  bf16* w1T  = (bf16*)alloc((size_t)NE * DIM * FFN * 2);
  bf16* vgT  = (bf16*)alloc((size_t)NE * DIM * FFN * 2);
  bf16* w2T  = (bf16*)alloc((size_t)NE * FFN * DIM * 2);
  bf16* outT = (bf16*)alloc((size_t)DIM * DIM * 2);
  bf16* Kbuf = (bf16*)alloc((size_t)NE * NTOK * DIM * 2);
  bf16* Vbuf = (bf16*)alloc((size_t)NE * NTOK * DIM * 2);
  bf16* Qbuf = (bf16*)alloc((size_t)NTOK * DIM * 2);
  bf16* aout = (bf16*)alloc((size_t)NTOK * DIM * 2);
  // aliases over dead buffers (stream-serialized, safe):
  bf16* H1   = Kbuf;                                    // (NTOK, FFN) after attn
  bf16* Ybuf = Vbuf;                                    // (NTOK, DIM)

  int* cursor = ctrl + 8;        // 8
  int* offs   = ctrl + 16;       // 9
  int* eidx   = ctrl + 32;       // 24
  int* mb     = ctrl + 56;       // 24

  hipMemsetAsync(d_ws, 0, 512 + 16 * DIM * 4, stream);  // ctrl + km

  cast_k<<<(NTOK * DIM / 8) / 256, 256, 0, stream>>>(x, xb);

  dim3 tb(32, 32);
  transpose_k<<<dim3(24, 24, 8), tb, 0, stream>>>(q_w, qwT, DIM, DIM);
  transpose_k<<<dim3(24, 24, 8), tb, 0, stream>>>(k_w, kwT, DIM, DIM);
  transpose_k<<<dim3(24, 24, 8), tb, 0, stream>>>(v_w, vwT, DIM, DIM);
  transpose_k<<<dim3(96, 24, 8), tb, 0, stream>>>(w1, w1T, DIM, FFN);
  transpose_k<<<dim3(96, 24, 8), tb, 0, stream>>>(vg, vgT, DIM, FFN);
  transpose_k<<<dim3(24, 96, 8), tb, 0, stream>>>(w2, w2T, FFN, DIM);
  transpose_k<<<dim3(24, 24, 1), tb, 0, stream>>>(outw, outT, DIM, DIM);

  router_k<<<NTOK, 64, 0, stream>>>(x, gate, idxb, probs);
  scan_k<<<1, 256, 0, stream>>>(idxb, probs, offs, eidx, mb, out + (size_t)NTOK * DIM);
  scatter_k<<<NTOK / 256, 256, 0, stream>>>(idxb, offs, cursor, perm);

  // fused dense K+V projections: per expert (2048x768)@(768x768) x2
  gemm_bt2<false, false, 0><<<dim3(6, 16, 8), 256, 0, stream>>>(
      xb, kwT, vwT, (size_t)DIM * DIM, Kbuf, Vbuf, (size_t)NTOK * DIM, DIM, DIM,
      nullptr, nullptr, nullptr, nullptr);
  kmean_k<<<dim3(3, 16, 8), 256, 0, stream>>>(Kbuf, km);

  // grouped Q projection (gather x rows, scatter to token order), slot-compacted
  gemm_bt<true, true, true, bf16><<<dim3(6, MAXSLOT, 1), 256, 0, stream>>>(
      xb, qwT, (size_t)DIM * DIM, Qbuf, 0, DIM, DIM, offs, perm, eidx, mb);

  attn_k<<<NTOK, 256, 0, stream>>>(Qbuf, Kbuf, Vbuf, km, idxb, aout);

  // fused grouped SwiGLU up-projection: H1 = silu(aout@w1T)*(aout@vgT)
  gemm_bt2<true, true, 1><<<dim3(24, MAXSLOT, 1), 256, 0, stream>>>(
      aout, w1T, vgT, (size_t)DIM * FFN, H1, nullptr, 0, FFN, DIM,
      offs, perm, eidx, mb);

  // grouped down-projection, scatter back to token order
  gemm_bt<true, false, true, bf16><<<dim3(6, MAXSLOT, 1), 256, 0, stream>>>(
      H1, w2T, (size_t)FFN * DIM, Ybuf, 0, DIM, FFN, offs, perm, eidx, mb);

  // final projection -> d_out (fp32)
  gemm_bt<false, false, false, float><<<dim3(6, 16, 1), 256, 0, stream>>>(
      Ybuf, outT, 0, out, 0, DIM, DIM, nullptr, nullptr, nullptr, nullptr);
}